// Round 1
// baseline (993.537 us; speedup 1.0000x reference)
//
#include <hip/hip_runtime.h>
#include <math.h>

#define NN 8
#define RR 256
#define CD 64      // in/out channel dim
#define MM 32      // kept modes per dim
#define KHN 64     // 2*MM kh values (rows 0..31 and 224..255)
#define KWN 32

// X1[((n*256+h)*32+kw)*64+c]        : DFT along w          (33.5 MB)
// X2[((n*64+khIdx)*32+kw)*64+c]     : DFT along h          (8.4 MB)
// X3[((n*64+khIdx)*32+kw)*64+o]     : spectral multiply    (8.4 MB)
// Y1[((n*256+h)*32+kw)*64+o]        : inverse DFT along h  (33.5 MB)

#define ANG 0.024543692606170259f  // 2*pi/256

// ---------------- K1: real DFT along w, keep kw=0..31 ----------------
__global__ __launch_bounds__(256) void k1_dft_w(const float* __restrict__ x,
                                                float2* __restrict__ X1) {
    __shared__ float xs[128 * 64];   // 32 KB, half-row chunks
    __shared__ float2 tab[256];
    int t = threadIdx.x;
    int nh = blockIdx.x;             // n*256 + h
    {
        float s, c;
        __sincosf((float)t * ANG, &s, &c);
        tab[t] = make_float2(c, -s); // forward: e^{-i theta}
    }
    int cch = t & 63;
    int g = t >> 6;                  // wave id 0..3 -> kw group
    float accR[8], accI[8];
#pragma unroll
    for (int j = 0; j < 8; ++j) { accR[j] = 0.f; accI[j] = 0.f; }
    const float* xrow = x + (size_t)nh * (RR * CD);
    for (int chunk = 0; chunk < 2; ++chunk) {
        __syncthreads();
#pragma unroll
        for (int k = 0; k < 32; ++k) {
            int idx = t + k * 256;
            xs[idx] = xrow[chunk * 8192 + idx];
        }
        __syncthreads();
        for (int wl = 0; wl < 128; ++wl) {
            int w = chunk * 128 + wl;
            float xv = xs[wl * 64 + cch];
#pragma unroll
            for (int j = 0; j < 8; ++j) {
                int kw = g * 8 + j;
                float2 tw = tab[(kw * w) & 255];   // broadcast within wave
                accR[j] += xv * tw.x;
                accI[j] += xv * tw.y;
            }
        }
    }
    float2* obase = X1 + (size_t)nh * (KWN * CD);
#pragma unroll
    for (int j = 0; j < 8; ++j) {
        int kw = g * 8 + j;
        obase[kw * CD + cch] = make_float2(accR[j], accI[j]);
    }
}

// ---------------- K2: complex DFT along h, keep kh in {0..31, 224..255} ----
__global__ __launch_bounds__(256) void k2_dft_h(const float2* __restrict__ X1,
                                                float2* __restrict__ X2) {
    __shared__ float2 xsh[64 * 64];  // 32 KB
    __shared__ float2 tab[256];
    int t = threadIdx.x;
    int n = blockIdx.x >> 5;
    int kw = blockIdx.x & 31;
    {
        float s, c;
        __sincosf((float)t * ANG, &s, &c);
        tab[t] = make_float2(c, -s);
    }
    int cch = t & 63;
    int g = t >> 6;
    float accR[16], accI[16];
#pragma unroll
    for (int j = 0; j < 16; ++j) { accR[j] = 0.f; accI[j] = 0.f; }
    for (int chunk = 0; chunk < 4; ++chunk) {
        __syncthreads();
#pragma unroll
        for (int k = 0; k < 16; ++k) {
            int idx = t + k * 256;   // 0..4095
            int hl = idx >> 6, c = idx & 63;
            int h = chunk * 64 + hl;
            xsh[idx] = X1[(((size_t)n * RR + h) * KWN + kw) * CD + c];
        }
        __syncthreads();
        for (int hl = 0; hl < 64; ++hl) {
            int h = chunk * 64 + hl;
            float2 xv = xsh[hl * 64 + cch];
#pragma unroll
            for (int j = 0; j < 16; ++j) {
                int khIdx = g * 16 + j;
                int kh = (khIdx < 32) ? khIdx : (192 + khIdx);  // 224..255
                float2 tw = tab[(kh * h) & 255];
                accR[j] += xv.x * tw.x - xv.y * tw.y;
                accI[j] += xv.x * tw.y + xv.y * tw.x;
            }
        }
    }
#pragma unroll
    for (int j = 0; j < 16; ++j) {
        int khIdx = g * 16 + j;
        X2[(((size_t)n * KHN + khIdx) * KWN + kw) * CD + cch] =
            make_float2(accR[j], accI[j]);
    }
}

// ---------------- K3: per-mode complex 64x64 channel matmul ----------------
__global__ __launch_bounds__(256) void k3_spectral(const float2* __restrict__ X2,
                                                   const float* __restrict__ w0,
                                                   const float* __restrict__ w1,
                                                   float2* __restrict__ X3) {
    __shared__ float WsR[4096], WsI[4096];  // 32 KB (SoA: conflict-free o reads)
    __shared__ float XsR[512], XsI[512];
    int t = threadIdx.x;
    int khIdx = blockIdx.x >> 5;
    int kw = blockIdx.x & 31;
    const float* wsrc = (khIdx < 32)
        ? (w0 + (size_t)(khIdx * 32 + kw) * (64 * 64 * 2))
        : (w1 + (size_t)((khIdx - 32) * 32 + kw) * (64 * 64 * 2));
    const float2* wsrc2 = (const float2*)wsrc;
#pragma unroll
    for (int k = 0; k < 16; ++k) {
        int idx = t + k * 256;
        float2 v = wsrc2[idx];        // (re, im) interleaved in source
        WsR[idx] = v.x; WsI[idx] = v.y;
    }
#pragma unroll
    for (int k = 0; k < 2; ++k) {
        int id2 = t + k * 256;
        int n = id2 >> 6, c = id2 & 63;
        float2 v = X2[(((size_t)n * KHN + khIdx) * KWN + kw) * CD + c];
        XsR[id2] = v.x; XsI[id2] = v.y;
    }
    __syncthreads();
    int o = t & 63;
    int ng = t >> 6;
#pragma unroll
    for (int p = 0; p < 2; ++p) {
        int n = ng + p * 4;
        float aR = 0.f, aI = 0.f;
#pragma unroll 8
        for (int i = 0; i < 64; ++i) {
            float xr = XsR[n * 64 + i], xi = XsI[n * 64 + i];  // broadcast
            float wr = WsR[i * 64 + o], wi = WsI[i * 64 + o];  // stride-1
            aR += xr * wr - xi * wi;
            aI += xr * wi + xi * wr;
        }
        X3[(((size_t)n * KHN + khIdx) * KWN + kw) * CD + o] = make_float2(aR, aI);
    }
}

// ---------------- K4: complex inverse DFT along h (full 256 h out) ---------
__global__ __launch_bounds__(256) void k4_idft_h(const float2* __restrict__ X3,
                                                 float2* __restrict__ Y1) {
    __shared__ float XsR[4096], XsI[4096];  // 32 KB
    __shared__ float2 tab[256];
    int t = threadIdx.x;
    int n = blockIdx.x >> 5;
    int kw = blockIdx.x & 31;
    {
        float s, c;
        __sincosf((float)t * ANG, &s, &c);
        tab[t] = make_float2(c, s);  // inverse: e^{+i theta}
    }
#pragma unroll
    for (int k = 0; k < 16; ++k) {
        int idx = t + k * 256;
        int khIdx = idx >> 6, o = idx & 63;
        float2 v = X3[(((size_t)n * KHN + khIdx) * KWN + kw) * CD + o];
        XsR[idx] = v.x; XsI[idx] = v.y;
    }
    __syncthreads();
    int o = t & 63, g = t >> 6;
    for (int iter = 0; iter < 64; ++iter) {
        int h = iter * 4 + g;
        float aR = 0.f, aI = 0.f;
#pragma unroll 8
        for (int khIdx = 0; khIdx < 64; ++khIdx) {
            int kh = (khIdx < 32) ? khIdx : (192 + khIdx);
            float2 tw = tab[(kh * h) & 255];
            float xr = XsR[khIdx * 64 + o], xi = XsI[khIdx * 64 + o];
            aR += xr * tw.x - xi * tw.y;
            aI += xr * tw.y + xi * tw.x;
        }
        Y1[(((size_t)n * RR + h) * KWN + kw) * CD + o] = make_float2(aR, aI);
    }
}

// ------- K5: c2r inverse along w + residual GEMM + bias + SiLU, fused ------
__global__ __launch_bounds__(256) void k5_final(const float2* __restrict__ Y1,
                                                const float* __restrict__ x,
                                                const float* __restrict__ res_w,
                                                const float* __restrict__ res_b,
                                                float* __restrict__ out) {
    __shared__ float YR[2048], YI[2048];  // 16 KB
    __shared__ float rw[4096];            // 16 KB
    __shared__ float xs[4096];            // 16 KB (64-w chunk of the x row)
    __shared__ float2 tab[256];
    __shared__ float bs[64];
    int t = threadIdx.x;
    int nh = blockIdx.x;
    {
        float s, c;
        __sincosf((float)t * ANG, &s, &c);
        tab[t] = make_float2(c, s);  // inverse
    }
#pragma unroll
    for (int k = 0; k < 8; ++k) {
        int idx = t + k * 256;       // kw*64 + o
        float2 v = Y1[(size_t)nh * (KWN * CD) + idx];
        YR[idx] = v.x; YI[idx] = v.y;
    }
#pragma unroll
    for (int k = 0; k < 16; ++k) rw[t + k * 256] = res_w[t + k * 256];
    if (t < 64) bs[t] = res_b[t];
    int o = t & 63, g = t >> 6;
    const float* xrow = x + (size_t)nh * (RR * CD);
    float* orow = out + (size_t)nh * (RR * CD);
    const float inv = 1.0f / 65536.0f;   // ortho norm: 1/256 fwd * 1/256 inv
    for (int wc = 0; wc < 4; ++wc) {
        __syncthreads();
#pragma unroll
        for (int k = 0; k < 16; ++k) {
            int idx = t + k * 256;
            xs[idx] = xrow[wc * 4096 + idx];
        }
        __syncthreads();
        for (int wl = 0; wl < 16; ++wl) {
            int wLoc = g * 16 + wl;
            int w = wc * 64 + wLoc;
            // residual: x[w,:] @ res_w[:,o] + b[o]
            float r = bs[o];
#pragma unroll 8
            for (int i = 0; i < 64; ++i)
                r += xs[wLoc * 64 + i] * rw[i * 64 + o];
            // c2r synthesis: Re(C0) + 2*sum_{kw=1..31} Re(C_kw e^{+i th})
            float spec = YR[o];
#pragma unroll 8
            for (int kw = 1; kw < 32; ++kw) {
                float2 tw = tab[(kw * w) & 255];
                spec += 2.0f * (YR[kw * 64 + o] * tw.x - YI[kw * 64 + o] * tw.y);
            }
            float v = spec * inv + r;
            float sv = v / (1.0f + __expf(-v));   // SiLU
            orow[w * 64 + o] = sv;
        }
    }
}

extern "C" void kernel_launch(void* const* d_in, const int* in_sizes, int n_in,
                              void* d_out, int out_size, void* d_ws, size_t ws_size,
                              hipStream_t stream) {
    const float* x     = (const float*)d_in[0];
    const float* w0    = (const float*)d_in[1];
    const float* w1    = (const float*)d_in[2];
    const float* res_w = (const float*)d_in[3];
    const float* res_b = (const float*)d_in[4];
    float* out = (float*)d_out;
    char* ws = (char*)d_ws;
    float2* X1 = (float2*)(ws);                    // 33,554,432 B
    float2* X2 = (float2*)(ws + 33554432);         //  8,388,608 B
    float2* X3 = (float2*)(ws + 41943040);         //  8,388,608 B
    float2* Y1 = (float2*)(ws + 50331648);         // 33,554,432 B

    k1_dft_w <<<NN * RR,   256, 0, stream>>>(x, X1);
    k2_dft_h <<<NN * KWN,  256, 0, stream>>>(X1, X2);
    k3_spectral<<<KHN * KWN, 256, 0, stream>>>(X2, w0, w1, X3);
    k4_idft_h<<<NN * KWN,  256, 0, stream>>>(X3, Y1);
    k5_final <<<NN * RR,   256, 0, stream>>>(Y1, x, res_w, res_b, out);
}

// Round 2
// 610.011 us; speedup vs baseline: 1.6287x; 1.6287x over previous
//
#include <hip/hip_runtime.h>
#include <math.h>

#define NN 8
#define RR 256
#define CD 64      // in/out channel dim
#define MM 32      // kept modes per dim
#define KHN 64     // 2*MM kh values (rows 0..31 and 224..255)
#define KWN 32

// X1[((n*256+h)*32+kw)*64+c]        : DFT along w          (33.5 MB)
// X2[((n*64+khIdx)*32+kw)*64+c]     : DFT along h          (8.4 MB)
// X3[((n*64+khIdx)*32+kw)*64+o]     : spectral multiply    (8.4 MB)
// Y1[((n*256+h)*32+kw)*64+o]        : inverse DFT along h  (33.5 MB)

#define ANG 0.024543692606170259f  // 2*pi/256
#define INVN (1.0f / 65536.0f)     // ortho norm, folded into k3 weights

typedef __attribute__((ext_vector_type(4))) float f32x4;
typedef __attribute__((ext_vector_type(8))) short short8;

__device__ inline unsigned short f2bf(float f) {
    union { float f; unsigned u; } v; v.f = f;
    unsigned r = v.u + 0x7FFF + ((v.u >> 16) & 1);
    return (unsigned short)(r >> 16);
}
__device__ inline unsigned pack2(float a, float b) {
    return (unsigned)f2bf(a) | ((unsigned)f2bf(b) << 16);
}

// ---------------- K1: real DFT along w as bf16 MFMA GEMM ----------------
// per nh: X1[kw'(64: R0..31,I0..31) x c(64)] = T[64x256] @ x^T[256x64]
__global__ __launch_bounds__(256) void k1_dft_w(const float* __restrict__ x,
                                                float2* __restrict__ X1) {
    __shared__ unsigned short At[64 * 264];   // 33792 B, pitch 264 halves (16B-mult)
    __shared__ unsigned short Bt[64 * 264];   // x^T: rows c, cols w
    __shared__ float2 tab[256];
    int t = threadIdx.x;
    int nh = blockIdx.x;
    {
        float s, c;
        __sincosf((float)t * ANG, &s, &c);
        tab[t] = make_float2(c, s);
    }
    __syncthreads();
    // At rows kw' 0..63: kw'<32 -> cos(2pi kw w/256); else -> -sin(...)
#pragma unroll
    for (int it = 0; it < 32; ++it) {
        int idx = t + it * 256;            // 0..8191 (pairs along w)
        int kwp = idx >> 7, wp = idx & 127;
        int kw = kwp & 31;
        int w0 = 2 * wp, w1 = w0 + 1;
        float a0, a1;
        if (kwp < 32) { a0 = tab[(kw * w0) & 255].x; a1 = tab[(kw * w1) & 255].x; }
        else          { a0 = -tab[(kw * w0) & 255].y; a1 = -tab[(kw * w1) & 255].y; }
        ((unsigned*)At)[(kwp * 264 + 2 * wp) >> 1] = pack2(a0, a1);
    }
    // Bt = x^T (bf16)
    const float* xr = x + (size_t)nh * (RR * CD);
#pragma unroll
    for (int it = 0; it < 32; ++it) {
        int idx = t + it * 256;            // 0..8191
        int q = idx >> 6, cc = idx & 63;   // w-pair q, channel cc
        float f0 = xr[(2 * q) * 64 + cc];
        float f1 = xr[(2 * q + 1) * 64 + cc];
        ((unsigned*)Bt)[(cc * 264 + 2 * q) >> 1] = pack2(f0, f1);
    }
    __syncthreads();
    int wv = t >> 6, l = t & 63, lm = l & 15, lq = l >> 4;
    f32x4 acc[4];
#pragma unroll
    for (int nt = 0; nt < 4; ++nt) { f32x4 z = {0.f, 0.f, 0.f, 0.f}; acc[nt] = z; }
#pragma unroll
    for (int ks = 0; ks < 8; ++ks) {
        short8 a = *(const short8*)&At[(wv * 16 + lm) * 264 + ks * 32 + lq * 8];
#pragma unroll
        for (int nt = 0; nt < 4; ++nt) {
            short8 b = *(const short8*)&Bt[(nt * 16 + lm) * 264 + ks * 32 + lq * 8];
            acc[nt] = __builtin_amdgcn_mfma_f32_16x16x32_bf16(a, b, acc[nt], 0, 0, 0);
        }
    }
    // D row = kw' = wv*16 + lq*4 + r (R if <32 else I), col c = nt*16 + lm
    float* X1f = (float*)(X1 + (size_t)nh * (KWN * CD));
#pragma unroll
    for (int nt = 0; nt < 4; ++nt)
#pragma unroll
        for (int r = 0; r < 4; ++r) {
            int kwp = wv * 16 + lq * 4 + r;
            int cc = nt * 16 + lm;
            int kw = kwp & 31, im = kwp >> 5;
            X1f[(kw * 64 + cc) * 2 + im] = acc[nt][r];
        }
}

// ---------------- K2: complex DFT along h, keep kh in {0..31, 224..255} ----
__global__ __launch_bounds__(256) void k2_dft_h(const float2* __restrict__ X1,
                                                float2* __restrict__ X2) {
    __shared__ float2 xsh[64 * 64];  // 32 KB
    __shared__ float2 tab[256];
    int t = threadIdx.x;
    int n = blockIdx.x >> 5;
    int kw = blockIdx.x & 31;
    {
        float s, c;
        __sincosf((float)t * ANG, &s, &c);
        tab[t] = make_float2(c, -s);
    }
    int cch = t & 63;
    int g = t >> 6;
    float accR[16], accI[16];
#pragma unroll
    for (int j = 0; j < 16; ++j) { accR[j] = 0.f; accI[j] = 0.f; }
    for (int chunk = 0; chunk < 4; ++chunk) {
        __syncthreads();
#pragma unroll
        for (int k = 0; k < 16; ++k) {
            int idx = t + k * 256;   // 0..4095
            int hl = idx >> 6, c = idx & 63;
            int h = chunk * 64 + hl;
            xsh[idx] = X1[(((size_t)n * RR + h) * KWN + kw) * CD + c];
        }
        __syncthreads();
        for (int hl = 0; hl < 64; ++hl) {
            int h = chunk * 64 + hl;
            float2 xv = xsh[hl * 64 + cch];
#pragma unroll
            for (int j = 0; j < 16; ++j) {
                int khIdx = g * 16 + j;
                int kh = (khIdx < 32) ? khIdx : (192 + khIdx);  // 224..255
                float2 tw = tab[(kh * h) & 255];
                accR[j] += xv.x * tw.x - xv.y * tw.y;
                accI[j] += xv.x * tw.y + xv.y * tw.x;
            }
        }
    }
#pragma unroll
    for (int j = 0; j < 16; ++j) {
        int khIdx = g * 16 + j;
        X2[(((size_t)n * KHN + khIdx) * KWN + kw) * CD + cch] =
            make_float2(accR[j], accI[j]);
    }
}

// ---------------- K3: per-mode complex 64x64 channel matmul ----------------
__global__ __launch_bounds__(256) void k3_spectral(const float2* __restrict__ X2,
                                                   const float* __restrict__ w0,
                                                   const float* __restrict__ w1,
                                                   float2* __restrict__ X3) {
    __shared__ float WsR[4096], WsI[4096];  // 32 KB
    __shared__ float XsR[512], XsI[512];
    int t = threadIdx.x;
    int khIdx = blockIdx.x >> 5;
    int kw = blockIdx.x & 31;
    const float* wsrc = (khIdx < 32)
        ? (w0 + (size_t)(khIdx * 32 + kw) * (64 * 64 * 2))
        : (w1 + (size_t)((khIdx - 32) * 32 + kw) * (64 * 64 * 2));
    const float2* wsrc2 = (const float2*)wsrc;
#pragma unroll
    for (int k = 0; k < 16; ++k) {
        int idx = t + k * 256;
        float2 v = wsrc2[idx];
        WsR[idx] = v.x * INVN; WsI[idx] = v.y * INVN;  // fold ortho norm here
    }
#pragma unroll
    for (int k = 0; k < 2; ++k) {
        int id2 = t + k * 256;
        int n = id2 >> 6, c = id2 & 63;
        float2 v = X2[(((size_t)n * KHN + khIdx) * KWN + kw) * CD + c];
        XsR[id2] = v.x; XsI[id2] = v.y;
    }
    __syncthreads();
    int o = t & 63;
    int ng = t >> 6;
#pragma unroll
    for (int p = 0; p < 2; ++p) {
        int n = ng + p * 4;
        float aR = 0.f, aI = 0.f;
#pragma unroll 8
        for (int i = 0; i < 64; ++i) {
            float xr = XsR[n * 64 + i], xi = XsI[n * 64 + i];
            float wr = WsR[i * 64 + o], wi = WsI[i * 64 + o];
            aR += xr * wr - xi * wi;
            aI += xr * wi + xi * wr;
        }
        X3[(((size_t)n * KHN + khIdx) * KWN + kw) * CD + o] = make_float2(aR, aI);
    }
}

// ---------------- K4: complex inverse DFT along h (full 256 h out) ---------
__global__ __launch_bounds__(256) void k4_idft_h(const float2* __restrict__ X3,
                                                 float2* __restrict__ Y1) {
    __shared__ float XsR[4096], XsI[4096];  // 32 KB
    __shared__ float2 tab[256];
    int t = threadIdx.x;
    int n = blockIdx.x >> 5;
    int kw = blockIdx.x & 31;
    {
        float s, c;
        __sincosf((float)t * ANG, &s, &c);
        tab[t] = make_float2(c, s);  // inverse: e^{+i theta}
    }
#pragma unroll
    for (int k = 0; k < 16; ++k) {
        int idx = t + k * 256;
        int khIdx = idx >> 6, o = idx & 63;
        float2 v = X3[(((size_t)n * KHN + khIdx) * KWN + kw) * CD + o];
        XsR[idx] = v.x; XsI[idx] = v.y;
    }
    __syncthreads();
    int o = t & 63, g = t >> 6;
    for (int iter = 0; iter < 64; ++iter) {
        int h = iter * 4 + g;
        float aR = 0.f, aI = 0.f;
#pragma unroll 8
        for (int khIdx = 0; khIdx < 64; ++khIdx) {
            int kh = (khIdx < 32) ? khIdx : (192 + khIdx);
            float2 tw = tab[(kh * h) & 255];
            float xr = XsR[khIdx * 64 + o], xi = XsI[khIdx * 64 + o];
            aR += xr * tw.x - xi * tw.y;
            aI += xr * tw.y + xi * tw.x;
        }
        Y1[(((size_t)n * RR + h) * KWN + kw) * CD + o] = make_float2(aR, aI);
    }
}

// ------- K5: fused c2r-synthesis + residual GEMM + bias + SiLU, bf16 MFMA --
// per (nh, half): out[128 x 64] = A[128 x 128] @ B[128 x 64] + bias, SiLU
// A cols: 0..31 = (kw==0 ? 1 : 2cos), 32 = 0, 33..63 = -2sin, 64..127 = x
// B rows: 0..31 = YR, 32..63 = YI (row32=0), 64..127 = res_w
__global__ __launch_bounds__(256) void k5_final(const float2* __restrict__ Y1,
                                                const float* __restrict__ x,
                                                const float* __restrict__ res_w,
                                                const float* __restrict__ res_b,
                                                float* __restrict__ out) {
    __shared__ unsigned short As[128 * 136];  // 34816 B, pitch 136 halves
    __shared__ unsigned short Bs[64 * 136];   // 17408 B (Bt: rows o, cols k)
    __shared__ float2 tab[256];
    __shared__ float bs[64];
    int t = threadIdx.x;
    int nh = blockIdx.x >> 1, half = blockIdx.x & 1;
    {
        float s, c;
        __sincosf((float)t * ANG, &s, &c);
        tab[t] = make_float2(c, s);  // (cos, sin)
    }
    if (t < 64) bs[t] = res_b[t];
    __syncthreads();
    // A twiddle cols (0..63)
#pragma unroll
    for (int it = 0; it < 16; ++it) {
        int idx = t + it * 256;          // 0..4095
        int r = idx >> 5, cp = idx & 31; // row r, col-pair cp
        int w = half * 128 + r;
        int c0 = 2 * cp, c1 = c0 + 1;
        float v0 = (c0 == 0) ? 1.0f
                 : (c0 < 32 ? 2.0f * tab[(c0 * w) & 255].x
                 : (c0 == 32 ? 0.0f : -2.0f * tab[((c0 - 32) * w) & 255].y));
        float v1 = (c1 < 32) ? 2.0f * tab[(c1 * w) & 255].x
                             : -2.0f * tab[((c1 - 32) * w) & 255].y;
        ((unsigned*)As)[(r * 136 + 2 * cp) >> 1] = pack2(v0, v1);
    }
    // A x cols (64..127)
    const float2* xr2 = (const float2*)(x + ((size_t)nh * 256 + half * 128) * 64);
#pragma unroll
    for (int it = 0; it < 16; ++it) {
        int idx = t + it * 256;
        int r = idx >> 5, cp = idx & 31;
        float2 v = xr2[r * 32 + cp];
        ((unsigned*)As)[(r * 136 + 64 + 2 * cp) >> 1] = pack2(v.x, v.y);
    }
    // B: Bt[o][k]
#pragma unroll
    for (int it = 0; it < 8; ++it) {
        int idx = t + it * 256;          // 0..2047
        int kw = idx >> 6, o = idx & 63;
        float2 v = Y1[(size_t)nh * (KWN * CD) + idx];
        Bs[o * 136 + kw] = f2bf(v.x);
        Bs[o * 136 + 32 + kw] = (kw == 0) ? (unsigned short)0 : f2bf(v.y);
    }
#pragma unroll
    for (int it = 0; it < 16; ++it) {
        int idx = t + it * 256;          // 0..4095
        int i = idx >> 6, o = idx & 63;
        Bs[o * 136 + 64 + i] = f2bf(res_w[idx]);
    }
    __syncthreads();
    int wv = t >> 6, l = t & 63, lm = l & 15, lq = l >> 4;
    f32x4 acc[2][4];
#pragma unroll
    for (int mt = 0; mt < 2; ++mt)
#pragma unroll
        for (int nt = 0; nt < 4; ++nt) { f32x4 z = {0.f, 0.f, 0.f, 0.f}; acc[mt][nt] = z; }
#pragma unroll
    for (int ks = 0; ks < 4; ++ks) {
        short8 a0 = *(const short8*)&As[(wv * 32 + lm) * 136 + ks * 32 + lq * 8];
        short8 a1 = *(const short8*)&As[(wv * 32 + 16 + lm) * 136 + ks * 32 + lq * 8];
#pragma unroll
        for (int nt = 0; nt < 4; ++nt) {
            short8 b = *(const short8*)&Bs[(nt * 16 + lm) * 136 + ks * 32 + lq * 8];
            acc[0][nt] = __builtin_amdgcn_mfma_f32_16x16x32_bf16(a0, b, acc[0][nt], 0, 0, 0);
            acc[1][nt] = __builtin_amdgcn_mfma_f32_16x16x32_bf16(a1, b, acc[1][nt], 0, 0, 0);
        }
    }
    float* orow = out + ((size_t)nh * 256 + half * 128) * 64;
#pragma unroll
    for (int mt = 0; mt < 2; ++mt)
#pragma unroll
        for (int nt = 0; nt < 4; ++nt)
#pragma unroll
            for (int r = 0; r < 4; ++r) {
                int wloc = wv * 32 + mt * 16 + lq * 4 + r;
                int o = nt * 16 + lm;
                float v = acc[mt][nt][r] + bs[o];
                float sv = v / (1.0f + __expf(-v));
                orow[wloc * 64 + o] = sv;
            }
}

extern "C" void kernel_launch(void* const* d_in, const int* in_sizes, int n_in,
                              void* d_out, int out_size, void* d_ws, size_t ws_size,
                              hipStream_t stream) {
    const float* x     = (const float*)d_in[0];
    const float* w0    = (const float*)d_in[1];
    const float* w1    = (const float*)d_in[2];
    const float* res_w = (const float*)d_in[3];
    const float* res_b = (const float*)d_in[4];
    float* out = (float*)d_out;
    char* ws = (char*)d_ws;
    float2* X1 = (float2*)(ws);                    // 33,554,432 B
    float2* X2 = (float2*)(ws + 33554432);         //  8,388,608 B
    float2* X3 = (float2*)(ws + 41943040);         //  8,388,608 B
    float2* Y1 = (float2*)(ws + 50331648);         // 33,554,432 B

    k1_dft_w  <<<NN * RR,      256, 0, stream>>>(x, X1);
    k2_dft_h  <<<NN * KWN,     256, 0, stream>>>(X1, X2);
    k3_spectral<<<KHN * KWN,   256, 0, stream>>>(X2, w0, w1, X3);
    k4_idft_h <<<NN * KWN,     256, 0, stream>>>(X3, Y1);
    k5_final  <<<NN * RR * 2,  256, 0, stream>>>(Y1, x, res_w, res_b, out);
}

// Round 3
// 371.880 us; speedup vs baseline: 2.6717x; 1.6403x over previous
//
#include <hip/hip_runtime.h>
#include <math.h>

#define NN 8
#define RR 256
#define CD 64      // in/out channel dim
#define MM 32      // kept modes per dim
#define KHN 64     // 2*MM kh values (rows 0..31 and 224..255)
#define KWN 32

#define ANG 0.024543692606170259f  // 2*pi/256
#define INVN (1.0f / 65536.0f)     // ortho norm, folded into k3 weights

typedef __attribute__((ext_vector_type(4))) float f32x4;
typedef __attribute__((ext_vector_type(8))) short short8;
typedef unsigned short u16;

__device__ inline u16 f2bf(float f) {
    union { float f; unsigned u; } v; v.f = f;
    unsigned r = v.u + 0x7FFF + ((v.u >> 16) & 1);
    return (u16)(r >> 16);
}
__device__ inline unsigned pack2(float a, float b) {
    return (unsigned)f2bf(a) | ((unsigned)f2bf(b) << 16);
}

// ---------------- K0: build twiddle operand tables (bf16) -------------------
// A2[128 x 512]: k2 A.  rows: kh' (0..63 R, 64..127 I); cols: k (h for xR | h for xI)
//   R row: [cos | sin];  I row: [-sin | cos]       (theta = kh*h*2pi/256)
// A4[512 x 128]: k4 A.  rows: (h R 0..255, h I 256..511); cols: (khIdx xR | khIdx xI)
//   R row: [cos | -sin]; I row: [sin | cos]
// T1[64 x 256]:  k1 A.  rows kw' (cos rows 0..31, -sin rows 32..63); cols w
// T5[256 x 64]:  k5 A twiddle cols. row w; col c: c==0->1, c<32->2cos, c==32->0, else->-2sin
__global__ __launch_bounds__(256) void k0_tables(u16* __restrict__ A2g,
                                                 u16* __restrict__ A4g,
                                                 u16* __restrict__ T1g,
                                                 u16* __restrict__ T5g) {
    int gid = blockIdx.x * 256 + threadIdx.x;   // 0..65535
    {
        int r = gid >> 9, k = gid & 511;
        int khIdx = r & 63, part = r >> 6;
        int kh = (khIdx < 32) ? khIdx : 192 + khIdx;
        int h = k & 255, kpart = k >> 8;
        float s, c;
        __sincosf((float)((kh * h) & 255) * ANG, &s, &c);
        float v = (part == 0) ? ((kpart == 0) ? c : s)
                              : ((kpart == 0) ? -s : c);
        A2g[gid] = f2bf(v);
    }
    {
        int r = gid >> 7, k = gid & 127;
        int h = r & 255, part = r >> 8;
        int khIdx = k & 63, kpart = k >> 6;
        int kh = (khIdx < 32) ? khIdx : 192 + khIdx;
        float s, c;
        __sincosf((float)((kh * h) & 255) * ANG, &s, &c);
        float v = (part == 0) ? ((kpart == 0) ? c : -s)
                              : ((kpart == 0) ? s : c);
        A4g[gid] = f2bf(v);
    }
    if (gid < 16384) {
        {
            int r = gid >> 8, w = gid & 255;
            float s, c;
            if (r < 32) { __sincosf((float)((r * w) & 255) * ANG, &s, &c); T1g[gid] = f2bf(c); }
            else        { __sincosf((float)(((r - 32) * w) & 255) * ANG, &s, &c); T1g[gid] = f2bf(-s); }
        }
        {
            int w = gid >> 6, c = gid & 63;
            float v;
            if (c == 0) v = 1.0f;
            else if (c < 32) { float s, co; __sincosf((float)((c * w) & 255) * ANG, &s, &co); v = 2.0f * co; }
            else if (c == 32) v = 0.0f;
            else { float s, co; __sincosf((float)(((c - 32) * w) & 255) * ANG, &s, &co); v = -2.0f * s; }
            T5g[gid] = f2bf(v);
        }
    }
}

// ---------------- K1: real DFT along w as bf16 MFMA GEMM ----------------
// per nh: [kw'(64) x c(64)] = T1[64x256] @ x^T[256x64]; out -> bf16 SoA planes
__global__ __launch_bounds__(256) void k1_dft_w(const float* __restrict__ x,
                                                const u16* __restrict__ T1g,
                                                u16* __restrict__ X1R,
                                                u16* __restrict__ X1I) {
    __shared__ __align__(16) u16 At[64 * 264];   // 33792 B
    __shared__ __align__(16) u16 Bt[64 * 264];
    int t = threadIdx.x;
    int nh = blockIdx.x;
#pragma unroll
    for (int it = 0; it < 8; ++it) {
        int idx = t + it * 256;           // 64 rows x 32 octs
        int row = idx >> 5, oct = idx & 31;
        *(uint4*)&At[row * 264 + oct * 8] = *(const uint4*)&T1g[row * 256 + oct * 8];
    }
    const float* xr = x + (size_t)nh * (RR * CD);
#pragma unroll
    for (int it = 0; it < 32; ++it) {
        int idx = t + it * 256;            // 0..8191
        int q = idx >> 6, cc = idx & 63;   // w-pair q, channel cc
        float f0 = xr[(2 * q) * 64 + cc];
        float f1 = xr[(2 * q + 1) * 64 + cc];
        ((unsigned*)Bt)[(cc * 264 + 2 * q) >> 1] = pack2(f0, f1);
    }
    __syncthreads();
    int wv = t >> 6, l = t & 63, lm = l & 15, lq = l >> 4;
    f32x4 acc[4];
#pragma unroll
    for (int nt = 0; nt < 4; ++nt) { f32x4 z = {0.f, 0.f, 0.f, 0.f}; acc[nt] = z; }
#pragma unroll
    for (int ks = 0; ks < 8; ++ks) {
        short8 a = *(const short8*)&At[(wv * 16 + lm) * 264 + ks * 32 + lq * 8];
#pragma unroll
        for (int nt = 0; nt < 4; ++nt) {
            short8 b = *(const short8*)&Bt[(nt * 16 + lm) * 264 + ks * 32 + lq * 8];
            acc[nt] = __builtin_amdgcn_mfma_f32_16x16x32_bf16(a, b, acc[nt], 0, 0, 0);
        }
    }
#pragma unroll
    for (int nt = 0; nt < 4; ++nt)
#pragma unroll
        for (int r = 0; r < 4; ++r) {
            int kwp = wv * 16 + lq * 4 + r;
            int cc = nt * 16 + lm;
            u16 v = f2bf(acc[nt][r]);
            if (kwp < 32) X1R[(size_t)nh * 2048 + kwp * 64 + cc] = v;
            else          X1I[(size_t)nh * 2048 + (kwp - 32) * 64 + cc] = v;
        }
}

// ---------------- K2: complex DFT along h as bf16 MFMA GEMM ----------------
// per (n,kw): [128 kh'-rows x 64 c] = A2[128x512] @ B[512x64]
__global__ __launch_bounds__(256) void k2_dft_h(const u16* __restrict__ X1R,
                                                const u16* __restrict__ X1I,
                                                const u16* __restrict__ A2g,
                                                float2* __restrict__ X2) {
    __shared__ __align__(16) u16 As[128 * 136];  // 34816 B
    __shared__ __align__(16) u16 Bs[64 * 136];   // 17408 B
    int t = threadIdx.x;
    int n = blockIdx.x >> 5, kw = blockIdx.x & 31;
    int wv = t >> 6, l = t & 63, lm = l & 15, lq = l >> 4;
    f32x4 acc[2][4];
#pragma unroll
    for (int mt = 0; mt < 2; ++mt)
#pragma unroll
        for (int nt = 0; nt < 4; ++nt) { f32x4 z = {0.f, 0.f, 0.f, 0.f}; acc[mt][nt] = z; }
    for (int ck = 0; ck < 4; ++ck) {
        const u16* plane = (ck < 2) ? X1R : X1I;
        int hb = ck & 1;
#pragma unroll
        for (int it = 0; it < 8; ++it) {        // A chunk: 128 rows x 16 octs
            int idx = t + it * 256;
            int row = idx >> 4, oct = idx & 15;
            *(uint4*)&As[row * 136 + oct * 8] =
                *(const uint4*)&A2g[row * 512 + ck * 128 + oct * 8];
        }
#pragma unroll
        for (int it = 0; it < 16; ++it) {       // B chunk: transpose to Bt[c][h]
            int idx = t + it * 256;             // 0..4095 (u32 pairs along c)
            int hl = idx >> 5, cp = idx & 31;
            int h = hb * 128 + hl;
            unsigned v = *(const unsigned*)&plane[(((size_t)n * 256 + h) * 32 + kw) * 64 + 2 * cp];
            Bs[(2 * cp) * 136 + hl] = (u16)(v & 0xFFFF);
            Bs[(2 * cp + 1) * 136 + hl] = (u16)(v >> 16);
        }
        __syncthreads();
#pragma unroll
        for (int ks = 0; ks < 4; ++ks) {
            short8 a0 = *(const short8*)&As[(wv * 32 + lm) * 136 + ks * 32 + lq * 8];
            short8 a1 = *(const short8*)&As[(wv * 32 + 16 + lm) * 136 + ks * 32 + lq * 8];
#pragma unroll
            for (int nt = 0; nt < 4; ++nt) {
                short8 b = *(const short8*)&Bs[(nt * 16 + lm) * 136 + ks * 32 + lq * 8];
                acc[0][nt] = __builtin_amdgcn_mfma_f32_16x16x32_bf16(a0, b, acc[0][nt], 0, 0, 0);
                acc[1][nt] = __builtin_amdgcn_mfma_f32_16x16x32_bf16(a1, b, acc[1][nt], 0, 0, 0);
            }
        }
        __syncthreads();
    }
#pragma unroll
    for (int mt = 0; mt < 2; ++mt)
#pragma unroll
        for (int nt = 0; nt < 4; ++nt)
#pragma unroll
            for (int r = 0; r < 4; ++r) {
                int m = wv * 32 + mt * 16 + lq * 4 + r;   // 0..127
                int c = nt * 16 + lm;
                float* dst = (float*)&X2[(((size_t)n * 64 + (m & 63)) * 32 + kw) * 64 + c];
                dst[m >> 6] = acc[mt][nt][r];
            }
}

// ---------------- K3: per-mode complex 64x64 channel matmul (fp32) ---------
__global__ __launch_bounds__(256) void k3_spectral(const float2* __restrict__ X2,
                                                   const float* __restrict__ w0,
                                                   const float* __restrict__ w1,
                                                   float2* __restrict__ X3) {
    __shared__ float WsR[4096], WsI[4096];
    __shared__ float XsR[512], XsI[512];
    int t = threadIdx.x;
    int khIdx = blockIdx.x >> 5;
    int kw = blockIdx.x & 31;
    const float* wsrc = (khIdx < 32)
        ? (w0 + (size_t)(khIdx * 32 + kw) * (64 * 64 * 2))
        : (w1 + (size_t)((khIdx - 32) * 32 + kw) * (64 * 64 * 2));
    const float2* wsrc2 = (const float2*)wsrc;
#pragma unroll
    for (int k = 0; k < 16; ++k) {
        int idx = t + k * 256;
        float2 v = wsrc2[idx];
        WsR[idx] = v.x * INVN; WsI[idx] = v.y * INVN;
    }
#pragma unroll
    for (int k = 0; k < 2; ++k) {
        int id2 = t + k * 256;
        int n = id2 >> 6, c = id2 & 63;
        float2 v = X2[(((size_t)n * KHN + khIdx) * KWN + kw) * CD + c];
        XsR[id2] = v.x; XsI[id2] = v.y;
    }
    __syncthreads();
    int o = t & 63;
    int ng = t >> 6;
#pragma unroll
    for (int p = 0; p < 2; ++p) {
        int n = ng + p * 4;
        float aR = 0.f, aI = 0.f;
#pragma unroll 8
        for (int i = 0; i < 64; ++i) {
            float xr = XsR[n * 64 + i], xi = XsI[n * 64 + i];
            float wr = WsR[i * 64 + o], wi = WsI[i * 64 + o];
            aR += xr * wr - xi * wi;
            aI += xr * wi + xi * wr;
        }
        X3[(((size_t)n * KHN + khIdx) * KWN + kw) * CD + o] = make_float2(aR, aI);
    }
}

// ---------------- K4: inverse DFT along h as bf16 MFMA GEMM ----------------
// per (n,kw,mh): rows (h,part=mh) 256 of 512; A4[512x128] @ B[128x64]
__global__ __launch_bounds__(256) void k4_idft_h(const float2* __restrict__ X3,
                                                 const u16* __restrict__ A4g,
                                                 u16* __restrict__ Y1R,
                                                 u16* __restrict__ Y1I) {
    __shared__ __align__(16) u16 As[128 * 136];
    __shared__ __align__(16) u16 Bs[64 * 136];
    int t = threadIdx.x;
    int b = blockIdx.x;
    int n = b >> 6, kw = (b >> 1) & 31, mh = b & 1;
#pragma unroll
    for (int it = 0; it < 16; ++it) {          // Bt[o][k]: k = khIdx | khIdx+64
        int idx = t + it * 256;                // 0..4095
        int khl = idx >> 6, o = idx & 63;
        float2 v = X3[(((size_t)n * KHN + khl) * KWN + kw) * CD + o];
        Bs[o * 136 + khl] = f2bf(v.x);
        Bs[o * 136 + 64 + khl] = f2bf(v.y);
    }
    int wv = t >> 6, l = t & 63, lm = l & 15, lq = l >> 4;
    u16* plane = mh ? Y1I : Y1R;
    for (int ac = 0; ac < 2; ++ac) {
#pragma unroll
        for (int it = 0; it < 8; ++it) {       // A chunk: 128 rows x 16 octs
            int idx = t + it * 256;
            int row = idx >> 4, oct = idx & 15;
            *(uint4*)&As[row * 136 + oct * 8] =
                *(const uint4*)&A4g[((size_t)(mh * 256 + ac * 128 + row)) * 128 + oct * 8];
        }
        __syncthreads();
        f32x4 acc[2][4];
#pragma unroll
        for (int mt = 0; mt < 2; ++mt)
#pragma unroll
            for (int nt = 0; nt < 4; ++nt) { f32x4 z = {0.f, 0.f, 0.f, 0.f}; acc[mt][nt] = z; }
#pragma unroll
        for (int ks = 0; ks < 4; ++ks) {
            short8 a0 = *(const short8*)&As[(wv * 32 + lm) * 136 + ks * 32 + lq * 8];
            short8 a1 = *(const short8*)&As[(wv * 32 + 16 + lm) * 136 + ks * 32 + lq * 8];
#pragma unroll
            for (int nt = 0; nt < 4; ++nt) {
                short8 bfr = *(const short8*)&Bs[(nt * 16 + lm) * 136 + ks * 32 + lq * 8];
                acc[0][nt] = __builtin_amdgcn_mfma_f32_16x16x32_bf16(a0, bfr, acc[0][nt], 0, 0, 0);
                acc[1][nt] = __builtin_amdgcn_mfma_f32_16x16x32_bf16(a1, bfr, acc[1][nt], 0, 0, 0);
            }
        }
#pragma unroll
        for (int mt = 0; mt < 2; ++mt)
#pragma unroll
            for (int nt = 0; nt < 4; ++nt)
#pragma unroll
                for (int r = 0; r < 4; ++r) {
                    int h = ac * 128 + wv * 32 + mt * 16 + lq * 4 + r;   // 0..255
                    int o = nt * 16 + lm;
                    plane[(((size_t)n * 256 + h) * 32 + kw) * 64 + o] = f2bf(acc[mt][nt][r]);
                }
        __syncthreads();
    }
}

// ------- K5: fused c2r-synthesis + residual GEMM + bias + SiLU, bf16 MFMA --
__global__ __launch_bounds__(256) void k5_final(const u16* __restrict__ YRp,
                                                const u16* __restrict__ YIp,
                                                const float* __restrict__ x,
                                                const float* __restrict__ res_w,
                                                const float* __restrict__ res_b,
                                                const u16* __restrict__ T5g,
                                                float* __restrict__ out) {
    __shared__ __align__(16) u16 As[128 * 136];
    __shared__ __align__(16) u16 Bs[64 * 136];
    __shared__ float bs[64];
    int t = threadIdx.x;
    int nh = blockIdx.x >> 1, half = blockIdx.x & 1;
    if (t < 64) bs[t] = res_b[t];
#pragma unroll
    for (int it = 0; it < 4; ++it) {           // A twiddle cols from T5
        int idx = t + it * 256;                // 128 rows x 8 octs
        int row = idx >> 3, oct = idx & 7;
        *(uint4*)&As[row * 136 + oct * 8] = *(const uint4*)&T5g[(half * 128 + row) * 64 + oct * 8];
    }
    const float2* xr2 = (const float2*)(x + ((size_t)nh * 256 + half * 128) * 64);
#pragma unroll
    for (int it = 0; it < 16; ++it) {          // A x cols (64..127)
        int idx = t + it * 256;
        int r = idx >> 5, cp = idx & 31;
        float2 v = xr2[r * 32 + cp];
        ((unsigned*)As)[(r * 136 + 64 + 2 * cp) >> 1] = pack2(v.x, v.y);
    }
#pragma unroll
    for (int it = 0; it < 4; ++it) {           // B rows 0..63: YR | YI
        int idx = t + it * 256;                // 0..1023: 32 kw x 32 o-pairs
        int kw = idx >> 5, op = idx & 31;
        unsigned vR = *(const unsigned*)&YRp[(size_t)nh * 2048 + kw * 64 + 2 * op];
        unsigned vI = *(const unsigned*)&YIp[(size_t)nh * 2048 + kw * 64 + 2 * op];
        Bs[(2 * op) * 136 + kw] = (u16)(vR & 0xFFFF);
        Bs[(2 * op + 1) * 136 + kw] = (u16)(vR >> 16);
        Bs[(2 * op) * 136 + 32 + kw] = (u16)(vI & 0xFFFF);
        Bs[(2 * op + 1) * 136 + 32 + kw] = (u16)(vI >> 16);
    }
#pragma unroll
    for (int it = 0; it < 16; ++it) {          // B rows 64..127: res_w
        int idx = t + it * 256;
        int i = idx >> 6, o = idx & 63;
        Bs[o * 136 + 64 + i] = f2bf(res_w[idx]);
    }
    __syncthreads();
    int wv = t >> 6, l = t & 63, lm = l & 15, lq = l >> 4;
    f32x4 acc[2][4];
#pragma unroll
    for (int mt = 0; mt < 2; ++mt)
#pragma unroll
        for (int nt = 0; nt < 4; ++nt) { f32x4 z = {0.f, 0.f, 0.f, 0.f}; acc[mt][nt] = z; }
#pragma unroll
    for (int ks = 0; ks < 4; ++ks) {
        short8 a0 = *(const short8*)&As[(wv * 32 + lm) * 136 + ks * 32 + lq * 8];
        short8 a1 = *(const short8*)&As[(wv * 32 + 16 + lm) * 136 + ks * 32 + lq * 8];
#pragma unroll
        for (int nt = 0; nt < 4; ++nt) {
            short8 b = *(const short8*)&Bs[(nt * 16 + lm) * 136 + ks * 32 + lq * 8];
            acc[0][nt] = __builtin_amdgcn_mfma_f32_16x16x32_bf16(a0, b, acc[0][nt], 0, 0, 0);
            acc[1][nt] = __builtin_amdgcn_mfma_f32_16x16x32_bf16(a1, b, acc[1][nt], 0, 0, 0);
        }
    }
    float* orow = out + ((size_t)nh * 256 + half * 128) * 64;
#pragma unroll
    for (int mt = 0; mt < 2; ++mt)
#pragma unroll
        for (int nt = 0; nt < 4; ++nt)
#pragma unroll
            for (int r = 0; r < 4; ++r) {
                int wloc = wv * 32 + mt * 16 + lq * 4 + r;
                int o = nt * 16 + lm;
                float v = acc[mt][nt][r] + bs[o];
                float sv = v / (1.0f + __expf(-v));
                orow[wloc * 64 + o] = sv;
            }
}

extern "C" void kernel_launch(void* const* d_in, const int* in_sizes, int n_in,
                              void* d_out, int out_size, void* d_ws, size_t ws_size,
                              hipStream_t stream) {
    const float* x     = (const float*)d_in[0];
    const float* w0    = (const float*)d_in[1];
    const float* w1    = (const float*)d_in[2];
    const float* res_w = (const float*)d_in[3];
    const float* res_b = (const float*)d_in[4];
    float* out = (float*)d_out;
    char* ws = (char*)d_ws;
    u16*    X1R = (u16*)(ws);                      //  8,388,608
    u16*    X1I = (u16*)(ws + 8388608);            //  8,388,608
    float2* X2  = (float2*)(ws + 16777216);        //  8,388,608
    float2* X3  = (float2*)(ws + 25165824);        //  8,388,608
    u16*    Y1R = (u16*)(ws + 33554432);           //  8,388,608
    u16*    Y1I = (u16*)(ws + 41943040);           //  8,388,608
    u16*    A2g = (u16*)(ws + 50331648);           //    131,072
    u16*    A4g = (u16*)(ws + 50462720);           //    131,072
    u16*    T1g = (u16*)(ws + 50593792);           //     32,768
    u16*    T5g = (u16*)(ws + 50626560);           //     32,768

    k0_tables  <<<256,          256, 0, stream>>>(A2g, A4g, T1g, T5g);
    k1_dft_w   <<<NN * RR,      256, 0, stream>>>(x, T1g, X1R, X1I);
    k2_dft_h   <<<NN * KWN,     256, 0, stream>>>(X1R, X1I, A2g, X2);
    k3_spectral<<<KHN * KWN,    256, 0, stream>>>(X2, w0, w1, X3);
    k4_idft_h  <<<NN * KWN * 2, 256, 0, stream>>>(X3, A4g, Y1R, Y1I);
    k5_final   <<<NN * RR * 2,  256, 0, stream>>>(Y1R, Y1I, x, res_w, res_b, T5g, out);
}